// Round 15
// baseline (156.339 us; speedup 1.0000x reference)
//
#include <hip/hip_runtime.h>
#include <hip/hip_bf16.h>
#include <cstdint>

// ---------------------------------------------------------------------------
// GNN encoder: 3 x { agg = segment_sum(z[src], dst); h = z + agg;
//                    t = relu(h@w1+b1); z = relu(t@w2+b2) }
// CSR build per call. z bf16 between layers. agg: 128B-slice gather (r7 best).
// MLP r15: 32-row x 256-col blocks, 256 thr / 4 waves (wave tile 32x64),
// W staged in 64-k slices -> LDS 64 KB -> 2 blocks/CU co-resident;
// grid 313 -> full CU coverage (r14: 157 blocks left 99 CUs idle).
// k-accum order per output unchanged -> bitwise-identical.
// scan: wave-shuffle (r14). wconv: coalesced LDS transpose (r9).
// ---------------------------------------------------------------------------

#define NNODES 10000
#define NEDGES 320000
#define DIN 128
#define DH 256

typedef __bf16 bf16x8 __attribute__((ext_vector_type(8)));
typedef unsigned short ushort8v __attribute__((ext_vector_type(8)));
typedef unsigned short ushort4v __attribute__((ext_vector_type(4)));
typedef float f32x4 __attribute__((ext_vector_type(4)));

__device__ __forceinline__ unsigned short f2bf(float f) {
    unsigned int u = __float_as_uint(f);
    unsigned int r = u + 0x7fffu + ((u >> 16) & 1u);   // round-to-nearest-even
    return (unsigned short)(r >> 16);
}
__device__ __forceinline__ float bf2f(unsigned short u) {
    return __uint_as_float(((unsigned int)u) << 16);
}

// --- fused prep: [0,40) zero cnt | [40] detect i32/i64 | [41,1291) xconv |
// rest: wconv via coalesced 32x32 LDS-transpose tiles
struct PrepArgs {
    const float* wsrc[6];
    unsigned short* wdst[6];
    int wkbits[6];
    const int* eb;
    int* flag;
    int* cnt;
    const float* x;
    unsigned short* xb;
};
#define PREP_ZERO_B 40
#define PREP_XCONV_B 1250
#define PREP_WCONV_B 352   // 32 tiles (m0: 4x8) + 5*64 tiles (8x8)
#define PREP_GRID (PREP_ZERO_B + 1 + PREP_XCONV_B + PREP_WCONV_B)

__global__ void prep_kernel(PrepArgs a) {
    __shared__ float tile[32][33];
    __shared__ int any;
    int bid = blockIdx.x;
    int tid = threadIdx.x;
    if (bid < PREP_ZERO_B) {
        int i = bid * 256 + tid;
        if (i < NNODES) a.cnt[i] = 0;
    } else if (bid == PREP_ZERO_B) {
        if (tid == 0) any = 0;
        __syncthreads();
        for (int i = tid; i < 1024; i += 256)
            if (a.eb[2 * i + 1] != 0) any = 1;
        __syncthreads();
        if (tid == 0) a.flag[0] = any;   // 1 => int32 storage, 0 => int64
    } else if (bid < PREP_ZERO_B + 1 + PREP_XCONV_B) {
        int i = (bid - PREP_ZERO_B - 1) * 256 + tid;
        if (i < NNODES * DIN / 4) {
            float4 v = reinterpret_cast<const float4*>(a.x)[i];
            ushort4v o = {f2bf(v.x), f2bf(v.y), f2bf(v.z), f2bf(v.w)};
            reinterpret_cast<ushort4v*>(a.xb)[i] = o;
        }
    } else {
        // transpose+convert one 32x32 tile: src fp32 [K][256] -> dst bf16 [256][K]
        int wb = bid - (PREP_ZERO_B + 1 + PREP_XCONV_B);
        int m, t32;
        if (wb < 32) { m = 0; t32 = wb; }
        else { m = 1 + (wb - 32) / 64; t32 = (wb - 32) % 64; }
        int kb = a.wkbits[m];
        int K = 1 << kb;
        int tc = t32 & 7, tr = t32 >> 3;          // tr < K/32
        int r = tid >> 3, c4 = (tid & 7) * 4;     // load coalesced rows
        float4 v = *reinterpret_cast<const float4*>(
            &a.wsrc[m][(size_t)(tr * 32 + r) * 256 + tc * 32 + c4]);
        tile[r][c4 + 0] = v.x; tile[r][c4 + 1] = v.y;
        tile[r][c4 + 2] = v.z; tile[r][c4 + 3] = v.w;
        __syncthreads();
        int cc = tid >> 3, k4 = (tid & 7) * 4;    // write coalesced dst rows
        ushort4v o = {f2bf(tile[k4 + 0][cc]), f2bf(tile[k4 + 1][cc]),
                      f2bf(tile[k4 + 2][cc]), f2bf(tile[k4 + 3][cc])};
        *reinterpret_cast<ushort4v*>(
            &a.wdst[m][(size_t)(tc * 32 + cc) * K + tr * 32 + k4]) = o;
    }
}

__device__ __forceinline__ int eload(const int* __restrict__ eb, int is32, long logical_idx) {
    return is32 ? eb[logical_idx] : eb[2 * logical_idx]; // little-endian low word
}

__global__ void hist_kernel(const int* __restrict__ eb, const int* __restrict__ flag,
                            int* __restrict__ cnt, int E) {
    int i = blockIdx.x * blockDim.x + threadIdx.x;
    if (i >= E) return;
    int is32 = flag[0];
    int d = eload(eb, is32, (long)E + i);
    atomicAdd(&cnt[d], 1);
}

// single-block exclusive scan over N counts -> offs[N+1], cursor copy.
// Wave-shuffle scan: per-wave __shfl_up inclusive scan, 16 wave sums scanned
// by wave 0, 2 barriers total.
__global__ __launch_bounds__(1024) void scan_kernel(const int* __restrict__ cnt,
                                                    int* __restrict__ offs,
                                                    int* __restrict__ cursor, int n) {
    __shared__ int wsums[16];
    int tid = threadIdx.x, lane = tid & 63, wid = tid >> 6;
    int per = (n + 1023) / 1024;          // 10 for n=10000
    int beg = tid * per;
    int local[16];
    int s = 0;
    for (int i = 0; i < per; ++i) {
        int idx = beg + i;
        int v = (idx < n) ? cnt[idx] : 0;
        local[i] = s;
        s += v;
    }
    int inc = s;                           // inclusive scan within wave
    for (int d = 1; d < 64; d <<= 1) {
        int y = __shfl_up(inc, d, 64);
        if (lane >= d) inc += y;
    }
    if (lane == 63) wsums[wid] = inc;
    __syncthreads();
    if (tid < 16) {
        int v = wsums[tid];
        for (int d = 1; d < 16; d <<= 1) {
            int y = __shfl_up(v, d, 64);
            if (tid >= d) v += y;
        }
        wsums[tid] = v;                    // inclusive wave-sum prefix
    }
    __syncthreads();
    int wbase = (wid > 0) ? wsums[wid - 1] : 0;
    int base = wbase + inc - s;            // exclusive prefix of this chunk
    for (int i = 0; i < per; ++i) {
        int idx = beg + i;
        if (idx < n) {
            int v = base + local[i];
            offs[idx] = v;
            cursor[idx] = v;
        }
    }
    if (tid == 1023) offs[n] = wbase + inc;
}

__global__ void scatter_kernel(const int* __restrict__ eb, const int* __restrict__ flag,
                               int* __restrict__ cursor, int* __restrict__ srcs, int E) {
    int i = blockIdx.x * blockDim.x + threadIdx.x;
    if (i >= E) return;
    int is32 = flag[0];
    int s = eload(eb, is32, (long)i);
    int d = eload(eb, is32, (long)E + i);
    int pos = atomicAdd(&cursor[d], 1);
    srcs[pos] = s;
}

// --- sliced bf16 aggregation: h[i] = z[i] + sum_{e in CSR[i]} z[src_e].
// 128B slices: LPN=8 lanes x ushort8 (16B) = one 128B cache line per
// node-slice. slice = bid & (NSLICE-1) -> round-robin XCD binding; per-XCD
// working set N*128B = 1.28 MB (L2-resident). 4 independent gather chains.
template <int D>
__global__ __launch_bounds__(256) void agg_add_sliced_kernel(const unsigned short* __restrict__ z,
                                                             const int* __restrict__ srcs,
                                                             const int* __restrict__ offs,
                                                             unsigned short* __restrict__ h, int n) {
    constexpr int NSLICE = (D * 2) / 128;  // 4 for D=256, 2 for D=128
    constexpr int LPN = 8;                 // 8 lanes x 16B = 128B per node-slice
    constexpr int NPB = 256 / LPN;         // 32 nodes per block
    int bid = blockIdx.x;
    int slice = bid & (NSLICE - 1);
    int ng = bid / NSLICE;
    int t = threadIdx.x;
    int node = ng * NPB + t / LPN;
    if (node >= n) return;
    int li = t % LPN;
    int col8 = slice * LPN + li;          // ushort8 column index within row
    const ushort8v* zb = reinterpret_cast<const ushort8v*>(z);
    const int ld8 = D / 8;
    int beg = offs[node], end = offs[node + 1];

    float a0[8] = {}, a1[8] = {}, a2[8] = {}, a3[8] = {};
    int e = beg;
    for (; e + 4 <= end; e += 4) {
        int s0 = srcs[e], s1 = srcs[e + 1], s2 = srcs[e + 2], s3 = srcs[e + 3];
        ushort8v v0 = zb[(size_t)s0 * ld8 + col8];
        ushort8v v1 = zb[(size_t)s1 * ld8 + col8];
        ushort8v v2 = zb[(size_t)s2 * ld8 + col8];
        ushort8v v3 = zb[(size_t)s3 * ld8 + col8];
#pragma unroll
        for (int j = 0; j < 8; ++j) {
            a0[j] += bf2f(v0[j]);
            a1[j] += bf2f(v1[j]);
            a2[j] += bf2f(v2[j]);
            a3[j] += bf2f(v3[j]);
        }
    }
    for (; e < end; ++e) {
        ushort8v v = zb[(size_t)srcs[e] * ld8 + col8];
#pragma unroll
        for (int j = 0; j < 8; ++j) a0[j] += bf2f(v[j]);
    }
    ushort8v zr = zb[(size_t)node * ld8 + col8];   // residual z term
    ushort8v o;
#pragma unroll
    for (int j = 0; j < 8; ++j) {
        float v = a0[j] + a1[j] + a2[j] + a3[j] + bf2f(zr[j]);
        o[j] = f2bf(v);
    }
    reinterpret_cast<ushort8v*>(h)[(size_t)node * ld8 + col8] = o;
}

// --- fused MLP r15: C = relu( relu(A@W1+b1) @ W2 + b2 ).
// 32-row x 256-col block, 256 thr / 4 waves; wave tile 32x64 (wc=wave),
// acc[2][4]. W staged in 64-k x 256-col slices (Bs 32 KB) -> LDS 64 KB
// -> 2 blocks/CU. Grid 313 -> full CU coverage. Per-output k-order = r14.
// MFMA layouts (m89-verified): A-frag row=lane&15, k=(lane>>4)*8+j;
// C/D col=lane&15, row=(lane>>4)*4+j.
template <int K, int OUT_BF16>
__global__ __launch_bounds__(256) void mlp_fused_kernel(const unsigned short* __restrict__ A,
                                                        const unsigned short* __restrict__ Wt1,
                                                        const float* __restrict__ b1,
                                                        const unsigned short* __restrict__ Wt2,
                                                        const float* __restrict__ b2,
                                                        void* __restrict__ C, int M) {
    constexpr int NK = K / 32;                   // A k-chunks (4 or 8)
    __shared__ unsigned short As[NK][4][32][8];  // 8/16 KB  full A tile
    __shared__ unsigned short Bs[2][4][256][8];  // 32 KB    64-k x 256-col W slice
    __shared__ unsigned short Ts[8][4][32][8];   // 16 KB    t tile
    int tid = threadIdx.x;
    int wave = tid >> 6, lane = tid & 63;
    int wc = wave;                               // 1x4 wave grid (col strip)
    int m0 = blockIdx.x * 32;
    int fr = lane & 15;        // fragment row/col
    int kc = lane >> 4;        // fragment k-chunk (== rg for C/D rows)

    f32x4 acc[2][4];
#pragma unroll
    for (int i = 0; i < 2; ++i)
#pragma unroll
        for (int j = 0; j < 4; ++j) acc[i][j] = (f32x4){0.f, 0.f, 0.f, 0.f};

    // ---- stage full A tile (row = tid>>3 in 0..31, chunk = tid&7 + i*8)
    {
        int row = tid >> 3, c0 = tid & 7;
        int gr = m0 + row;
#pragma unroll
        for (int i = 0; i < K / 64; ++i) {
            int chunk = c0 + i * 8;
            ushort8v av = {0, 0, 0, 0, 0, 0, 0, 0};
            if (gr < M) av = *reinterpret_cast<const ushort8v*>(&A[(size_t)gr * K + chunk * 8]);
            *reinterpret_cast<ushort8v*>(&As[chunk >> 2][chunk & 3][row][0]) = av;
        }
    }
    int scol = tid >> 2;       // staging col 0..63
    int sscn = tid & 3;        // staging k-subchunk 0..3

    // ---- phase 1: t = relu(A @ W1 + b1) -> Ts; K/64 stages of 64-k
#pragma unroll
    for (int st = 0; st < K / 64; ++st) {
#pragma unroll
        for (int cp = 0; cp < 4; ++cp) {
            int c = cp * 64 + scol;
#pragma unroll
            for (int kk = 0; kk < 2; ++kk)
                *reinterpret_cast<ushort8v*>(&Bs[kk][sscn][c][0]) =
                    *reinterpret_cast<const ushort8v*>(&Wt1[(size_t)c * K + st * 64 + kk * 32 + sscn * 8]);
        }
        __syncthreads();       // As (st=0) + Bs ready
#pragma unroll
        for (int kk = 0; kk < 2; ++kk) {
            bf16x8 af[2];
#pragma unroll
            for (int i = 0; i < 2; ++i)
                af[i] = __builtin_bit_cast(bf16x8,
                    *reinterpret_cast<const ushort8v*>(&As[st * 2 + kk][kc][i * 16 + fr][0]));
#pragma unroll
            for (int j = 0; j < 4; ++j) {
                bf16x8 bf = __builtin_bit_cast(bf16x8,
                    *reinterpret_cast<const ushort8v*>(&Bs[kk][kc][wc * 64 + j * 16 + fr][0]));
#pragma unroll
                for (int i = 0; i < 2; ++i)
                    acc[i][j] = __builtin_amdgcn_mfma_f32_16x16x32_bf16(af[i], bf, acc[i][j], 0, 0, 0);
            }
        }
        __syncthreads();       // Bs consumed, safe to overwrite
    }
    // ---- epilogue 1 -> Ts[col>>5][(col>>3)&3][row][col&7]
#pragma unroll
    for (int i = 0; i < 2; ++i)
#pragma unroll
        for (int j = 0; j < 4; ++j) {
            int col = wc * 64 + j * 16 + fr;
            float bb = b1[col];
#pragma unroll
            for (int jj = 0; jj < 4; ++jj) {
                int row = i * 16 + kc * 4 + jj;
                float v = fmaxf(acc[i][j][jj] + bb, 0.f);
                Ts[col >> 5][(col >> 3) & 3][row][col & 7] = f2bf(v);
            }
            acc[i][j] = (f32x4){0.f, 0.f, 0.f, 0.f};
        }

    // ---- phase 2: z = relu(t @ W2 + b2); t k-dim 256 -> 4 stages
#pragma unroll
    for (int st = 0; st < 4; ++st) {
#pragma unroll
        for (int cp = 0; cp < 4; ++cp) {
            int c = cp * 64 + scol;
#pragma unroll
            for (int kk = 0; kk < 2; ++kk)
                *reinterpret_cast<ushort8v*>(&Bs[kk][sscn][c][0]) =
                    *reinterpret_cast<const ushort8v*>(&Wt2[(size_t)c * 256 + st * 64 + kk * 32 + sscn * 8]);
        }
        __syncthreads();       // Ts (epi1, st=0) + Bs ready
#pragma unroll
        for (int kk = 0; kk < 2; ++kk) {
            bf16x8 af[2];
#pragma unroll
            for (int i = 0; i < 2; ++i)
                af[i] = __builtin_bit_cast(bf16x8,
                    *reinterpret_cast<const ushort8v*>(&Ts[st * 2 + kk][kc][i * 16 + fr][0]));
#pragma unroll
            for (int j = 0; j < 4; ++j) {
                bf16x8 bf = __builtin_bit_cast(bf16x8,
                    *reinterpret_cast<const ushort8v*>(&Bs[kk][kc][wc * 64 + j * 16 + fr][0]));
#pragma unroll
                for (int i = 0; i < 2; ++i)
                    acc[i][j] = __builtin_amdgcn_mfma_f32_16x16x32_bf16(af[i], bf, acc[i][j], 0, 0, 0);
            }
        }
        __syncthreads();
    }
    // ---- epilogue 2 -> global
#pragma unroll
    for (int i = 0; i < 2; ++i)
#pragma unroll
        for (int j = 0; j < 4; ++j) {
            int col = wc * 64 + j * 16 + fr;
            float bb = b2[col];
#pragma unroll
            for (int jj = 0; jj < 4; ++jj) {
                int row = m0 + i * 16 + kc * 4 + jj;
                if (row < M) {
                    float v = fmaxf(acc[i][j][jj] + bb, 0.f);
                    if (OUT_BF16)
                        ((unsigned short*)C)[(size_t)row * 256 + col] = f2bf(v);
                    else
                        ((float*)C)[(size_t)row * 256 + col] = v;
                }
            }
        }
}

extern "C" void kernel_launch(void* const* d_in, const int* in_sizes, int n_in,
                              void* d_out, int out_size, void* d_ws, size_t ws_size,
                              hipStream_t stream) {
    const float* x = (const float*)d_in[0];
    const int* eb = (const int*)d_in[1];
    const int E = NEDGES;
    const int N = NNODES;

    const float* w1[3] = {(const float*)d_in[2], (const float*)d_in[6], (const float*)d_in[10]};
    const float* b1[3] = {(const float*)d_in[3], (const float*)d_in[7], (const float*)d_in[11]};
    const float* w2[3] = {(const float*)d_in[4], (const float*)d_in[8], (const float*)d_in[12]};
    const float* b2[3] = {(const float*)d_in[5], (const float*)d_in[9], (const float*)d_in[13]};

    // workspace layout
    char* ws = (char*)d_ws;
    size_t off = 0;
    auto alloc = [&](size_t bytes) {
        void* p = ws + off;
        off += (bytes + 255) & ~(size_t)255;
        return p;
    };
    int* flag   = (int*)alloc(4);
    int* cnt    = (int*)alloc((size_t)N * 4);
    int* offs   = (int*)alloc((size_t)(N + 1) * 4);
    int* cursor = (int*)alloc((size_t)N * 4);
    int* srcs   = (int*)alloc((size_t)E * 4);
    unsigned short* xb   = (unsigned short*)alloc((size_t)N * DIN * 2);
    unsigned short* zbuf = (unsigned short*)alloc((size_t)N * DH * 2);
    unsigned short* hbuf = (unsigned short*)alloc((size_t)N * DH * 2);
    unsigned short* wt[6];
    wt[0] = (unsigned short*)alloc((size_t)DIN * DH * 2);          // w1_0^T: 256x128
    for (int i = 1; i < 6; ++i) wt[i] = (unsigned short*)alloc((size_t)DH * DH * 2);
    (void)ws_size; (void)n_in; (void)out_size; (void)in_sizes;

    // --- fused prep (zero cnt | detect | x->bf16 | weights ->bf16 transposed)
    PrepArgs pa;
    pa.wsrc[0] = w1[0]; pa.wsrc[1] = w2[0]; pa.wsrc[2] = w1[1];
    pa.wsrc[3] = w2[1]; pa.wsrc[4] = w1[2]; pa.wsrc[5] = w2[2];
    for (int i = 0; i < 6; ++i) pa.wdst[i] = wt[i];
    pa.wkbits[0] = 7;
    for (int i = 1; i < 6; ++i) pa.wkbits[i] = 8;
    pa.eb = eb; pa.flag = flag; pa.cnt = cnt; pa.x = x; pa.xb = xb;
    prep_kernel<<<PREP_GRID, 256, 0, stream>>>(pa);

    // --- CSR build
    hist_kernel<<<(E + 255) / 256, 256, 0, stream>>>(eb, flag, cnt, E);
    scan_kernel<<<1, 1024, 0, stream>>>(cnt, offs, cursor, N);
    scatter_kernel<<<(E + 255) / 256, 256, 0, stream>>>(eb, flag, cursor, srcs, E);

    int mlp_grid = (N + 31) / 32;               // 313 blocks
    int agg_blocks_256 = ((N + 31) / 32) * 4;   // D=256: 32 nodes/block, 4 slices
    int agg_blocks_128 = ((N + 31) / 32) * 2;   // D=128: 32 nodes/block, 2 slices

    // --- layer 0 (K = 128)
    agg_add_sliced_kernel<128><<<agg_blocks_128, 256, 0, stream>>>(xb, srcs, offs, hbuf, N);
    mlp_fused_kernel<128, 1><<<mlp_grid, 256, 0, stream>>>(hbuf, wt[0], b1[0], wt[1], b2[0], zbuf, N);

    // --- layer 1
    agg_add_sliced_kernel<256><<<agg_blocks_256, 256, 0, stream>>>(zbuf, srcs, offs, hbuf, N);
    mlp_fused_kernel<256, 1><<<mlp_grid, 256, 0, stream>>>(hbuf, wt[2], b1[1], wt[3], b2[1], zbuf, N);

    // --- layer 2 (final output fp32 to d_out)
    agg_add_sliced_kernel<256><<<agg_blocks_256, 256, 0, stream>>>(zbuf, srcs, offs, hbuf, N);
    mlp_fused_kernel<256, 0><<<mlp_grid, 256, 0, stream>>>(hbuf, wt[4], b1[2], wt[5], b2[2], (float*)d_out, N);
}

// Round 16
// 146.683 us; speedup vs baseline: 1.0658x; 1.0658x over previous
//
#include <hip/hip_runtime.h>
#include <hip/hip_bf16.h>
#include <cstdint>

// ---------------------------------------------------------------------------
// GNN encoder: 3 x { agg = segment_sum(z[src], dst); h = z + agg;
//                    t = relu(h@w1+b1); z = relu(t@w2+b2) }
// CSR build per call. z bf16 between layers. agg: 128B-slice gather (r7 best).
// MLP r16 = r14 (64-row, 8 waves/512thr, 32x64 wave tiles, 128-k W slices)
//   + T14 async-stage split: next W slice prefetched into REGISTERS during
//   current stage's MFMA, written to LDS after the consumed-barrier.
//   Same values -> same Bs slots -> bitwise-identical. (r15's 32-row blocks
//   REVERTED: doubled weight traffic + barriers, +9.6us.)
// scan: wave-shuffle (r14). wconv: coalesced LDS transpose (r9).
// ---------------------------------------------------------------------------

#define NNODES 10000
#define NEDGES 320000
#define DIN 128
#define DH 256

typedef __bf16 bf16x8 __attribute__((ext_vector_type(8)));
typedef unsigned short ushort8v __attribute__((ext_vector_type(8)));
typedef unsigned short ushort4v __attribute__((ext_vector_type(4)));
typedef float f32x4 __attribute__((ext_vector_type(4)));

__device__ __forceinline__ unsigned short f2bf(float f) {
    unsigned int u = __float_as_uint(f);
    unsigned int r = u + 0x7fffu + ((u >> 16) & 1u);   // round-to-nearest-even
    return (unsigned short)(r >> 16);
}
__device__ __forceinline__ float bf2f(unsigned short u) {
    return __uint_as_float(((unsigned int)u) << 16);
}

// --- fused prep: [0,40) zero cnt | [40] detect i32/i64 | [41,1291) xconv |
// rest: wconv via coalesced 32x32 LDS-transpose tiles
struct PrepArgs {
    const float* wsrc[6];
    unsigned short* wdst[6];
    int wkbits[6];
    const int* eb;
    int* flag;
    int* cnt;
    const float* x;
    unsigned short* xb;
};
#define PREP_ZERO_B 40
#define PREP_XCONV_B 1250
#define PREP_WCONV_B 352   // 32 tiles (m0: 4x8) + 5*64 tiles (8x8)
#define PREP_GRID (PREP_ZERO_B + 1 + PREP_XCONV_B + PREP_WCONV_B)

__global__ void prep_kernel(PrepArgs a) {
    __shared__ float tile[32][33];
    __shared__ int any;
    int bid = blockIdx.x;
    int tid = threadIdx.x;
    if (bid < PREP_ZERO_B) {
        int i = bid * 256 + tid;
        if (i < NNODES) a.cnt[i] = 0;
    } else if (bid == PREP_ZERO_B) {
        if (tid == 0) any = 0;
        __syncthreads();
        for (int i = tid; i < 1024; i += 256)
            if (a.eb[2 * i + 1] != 0) any = 1;
        __syncthreads();
        if (tid == 0) a.flag[0] = any;   // 1 => int32 storage, 0 => int64
    } else if (bid < PREP_ZERO_B + 1 + PREP_XCONV_B) {
        int i = (bid - PREP_ZERO_B - 1) * 256 + tid;
        if (i < NNODES * DIN / 4) {
            float4 v = reinterpret_cast<const float4*>(a.x)[i];
            ushort4v o = {f2bf(v.x), f2bf(v.y), f2bf(v.z), f2bf(v.w)};
            reinterpret_cast<ushort4v*>(a.xb)[i] = o;
        }
    } else {
        // transpose+convert one 32x32 tile: src fp32 [K][256] -> dst bf16 [256][K]
        int wb = bid - (PREP_ZERO_B + 1 + PREP_XCONV_B);
        int m, t32;
        if (wb < 32) { m = 0; t32 = wb; }
        else { m = 1 + (wb - 32) / 64; t32 = (wb - 32) % 64; }
        int kb = a.wkbits[m];
        int K = 1 << kb;
        int tc = t32 & 7, tr = t32 >> 3;          // tr < K/32
        int r = tid >> 3, c4 = (tid & 7) * 4;     // load coalesced rows
        float4 v = *reinterpret_cast<const float4*>(
            &a.wsrc[m][(size_t)(tr * 32 + r) * 256 + tc * 32 + c4]);
        tile[r][c4 + 0] = v.x; tile[r][c4 + 1] = v.y;
        tile[r][c4 + 2] = v.z; tile[r][c4 + 3] = v.w;
        __syncthreads();
        int cc = tid >> 3, k4 = (tid & 7) * 4;    // write coalesced dst rows
        ushort4v o = {f2bf(tile[k4 + 0][cc]), f2bf(tile[k4 + 1][cc]),
                      f2bf(tile[k4 + 2][cc]), f2bf(tile[k4 + 3][cc])};
        *reinterpret_cast<ushort4v*>(
            &a.wdst[m][(size_t)(tc * 32 + cc) * K + tr * 32 + k4]) = o;
    }
}

__device__ __forceinline__ int eload(const int* __restrict__ eb, int is32, long logical_idx) {
    return is32 ? eb[logical_idx] : eb[2 * logical_idx]; // little-endian low word
}

__global__ void hist_kernel(const int* __restrict__ eb, const int* __restrict__ flag,
                            int* __restrict__ cnt, int E) {
    int i = blockIdx.x * blockDim.x + threadIdx.x;
    if (i >= E) return;
    int is32 = flag[0];
    int d = eload(eb, is32, (long)E + i);
    atomicAdd(&cnt[d], 1);
}

// single-block exclusive scan over N counts -> offs[N+1], cursor copy.
// Wave-shuffle scan: per-wave __shfl_up inclusive scan, 16 wave sums scanned
// by wave 0, 2 barriers total.
__global__ __launch_bounds__(1024) void scan_kernel(const int* __restrict__ cnt,
                                                    int* __restrict__ offs,
                                                    int* __restrict__ cursor, int n) {
    __shared__ int wsums[16];
    int tid = threadIdx.x, lane = tid & 63, wid = tid >> 6;
    int per = (n + 1023) / 1024;          // 10 for n=10000
    int beg = tid * per;
    int local[16];
    int s = 0;
    for (int i = 0; i < per; ++i) {
        int idx = beg + i;
        int v = (idx < n) ? cnt[idx] : 0;
        local[i] = s;
        s += v;
    }
    int inc = s;                           // inclusive scan within wave
    for (int d = 1; d < 64; d <<= 1) {
        int y = __shfl_up(inc, d, 64);
        if (lane >= d) inc += y;
    }
    if (lane == 63) wsums[wid] = inc;
    __syncthreads();
    if (tid < 16) {
        int v = wsums[tid];
        for (int d = 1; d < 16; d <<= 1) {
            int y = __shfl_up(v, d, 64);
            if (tid >= d) v += y;
        }
        wsums[tid] = v;                    // inclusive wave-sum prefix
    }
    __syncthreads();
    int wbase = (wid > 0) ? wsums[wid - 1] : 0;
    int base = wbase + inc - s;            // exclusive prefix of this chunk
    for (int i = 0; i < per; ++i) {
        int idx = beg + i;
        if (idx < n) {
            int v = base + local[i];
            offs[idx] = v;
            cursor[idx] = v;
        }
    }
    if (tid == 1023) offs[n] = wbase + inc;
}

__global__ void scatter_kernel(const int* __restrict__ eb, const int* __restrict__ flag,
                               int* __restrict__ cursor, int* __restrict__ srcs, int E) {
    int i = blockIdx.x * blockDim.x + threadIdx.x;
    if (i >= E) return;
    int is32 = flag[0];
    int s = eload(eb, is32, (long)i);
    int d = eload(eb, is32, (long)E + i);
    int pos = atomicAdd(&cursor[d], 1);
    srcs[pos] = s;
}

// --- sliced bf16 aggregation: h[i] = z[i] + sum_{e in CSR[i]} z[src_e].
// 128B slices: LPN=8 lanes x ushort8 (16B) = one 128B cache line per
// node-slice. slice = bid & (NSLICE-1) -> round-robin XCD binding; per-XCD
// working set N*128B = 1.28 MB (L2-resident). 4 independent gather chains.
template <int D>
__global__ __launch_bounds__(256) void agg_add_sliced_kernel(const unsigned short* __restrict__ z,
                                                             const int* __restrict__ srcs,
                                                             const int* __restrict__ offs,
                                                             unsigned short* __restrict__ h, int n) {
    constexpr int NSLICE = (D * 2) / 128;  // 4 for D=256, 2 for D=128
    constexpr int LPN = 8;                 // 8 lanes x 16B = 128B per node-slice
    constexpr int NPB = 256 / LPN;         // 32 nodes per block
    int bid = blockIdx.x;
    int slice = bid & (NSLICE - 1);
    int ng = bid / NSLICE;
    int t = threadIdx.x;
    int node = ng * NPB + t / LPN;
    if (node >= n) return;
    int li = t % LPN;
    int col8 = slice * LPN + li;          // ushort8 column index within row
    const ushort8v* zb = reinterpret_cast<const ushort8v*>(z);
    const int ld8 = D / 8;
    int beg = offs[node], end = offs[node + 1];

    float a0[8] = {}, a1[8] = {}, a2[8] = {}, a3[8] = {};
    int e = beg;
    for (; e + 4 <= end; e += 4) {
        int s0 = srcs[e], s1 = srcs[e + 1], s2 = srcs[e + 2], s3 = srcs[e + 3];
        ushort8v v0 = zb[(size_t)s0 * ld8 + col8];
        ushort8v v1 = zb[(size_t)s1 * ld8 + col8];
        ushort8v v2 = zb[(size_t)s2 * ld8 + col8];
        ushort8v v3 = zb[(size_t)s3 * ld8 + col8];
#pragma unroll
        for (int j = 0; j < 8; ++j) {
            a0[j] += bf2f(v0[j]);
            a1[j] += bf2f(v1[j]);
            a2[j] += bf2f(v2[j]);
            a3[j] += bf2f(v3[j]);
        }
    }
    for (; e < end; ++e) {
        ushort8v v = zb[(size_t)srcs[e] * ld8 + col8];
#pragma unroll
        for (int j = 0; j < 8; ++j) a0[j] += bf2f(v[j]);
    }
    ushort8v zr = zb[(size_t)node * ld8 + col8];   // residual z term
    ushort8v o;
#pragma unroll
    for (int j = 0; j < 8; ++j) {
        float v = a0[j] + a1[j] + a2[j] + a3[j] + bf2f(zr[j]);
        o[j] = f2bf(v);
    }
    reinterpret_cast<ushort8v*>(h)[(size_t)node * ld8 + col8] = o;
}

// --- fused MLP r16: C = relu( relu(A@W1+b1) @ W2 + b2 ).
// 512 threads / 8 waves; wave grid 2x4 (wr=wave>>2, wc=wave&3), 32x64/wave.
// T14 async-stage: next W slice -> 8 ushort8v regs during current MFMA;
// regs -> LDS after consumed-barrier. Same Bs slots, same k-order.
// MFMA layouts (m89-verified): A-frag row=lane&15, k=(lane>>4)*8+j;
// C/D col=lane&15, row=(lane>>4)*4+j.
template <int K, int OUT_BF16>
__global__ __launch_bounds__(512) void mlp_fused_kernel(const unsigned short* __restrict__ A,
                                                        const unsigned short* __restrict__ Wt1,
                                                        const float* __restrict__ b1,
                                                        const unsigned short* __restrict__ Wt2,
                                                        const float* __restrict__ b2,
                                                        void* __restrict__ C, int M) {
    constexpr int NK = K / 32;                   // k-chunks in A (4 or 8)
    constexpr int NST1 = K / 128;                // phase-1 W stages (1 or 2)
    __shared__ unsigned short As[NK][4][64][8];  // 16/32 KB  full A tile
    __shared__ unsigned short Bs[4][4][256][8];  // 64 KB     128-k x 256-col W slice
    __shared__ unsigned short Ts[8][4][64][8];   // 32 KB     t tile
    int tid = threadIdx.x;
    int wave = tid >> 6, lane = tid & 63;
    int wr = wave >> 2, wc = wave & 3;           // 2x4 wave grid
    int m0 = blockIdx.x * 64;
    int fr = lane & 15;        // fragment row/col
    int kc = lane >> 4;        // fragment k-chunk (== rg for C/D rows)
    int scol = tid >> 2;       // staging col 0..127
    int sscn = tid & 3;        // staging k-subchunk 0..3

    f32x4 acc[2][4];
#pragma unroll
    for (int i = 0; i < 2; ++i)
#pragma unroll
        for (int j = 0; j < 4; ++j) acc[i][j] = (f32x4){0.f, 0.f, 0.f, 0.f};

    ushort8v wreg[8];
#define LOAD_W(Wp, ldk, st)                                                   \
    {                                                                         \
        _Pragma("unroll")                                                     \
        for (int cp = 0; cp < 2; ++cp) {                                      \
            _Pragma("unroll")                                                 \
            for (int kk = 0; kk < 4; ++kk)                                    \
                wreg[cp * 4 + kk] = *reinterpret_cast<const ushort8v*>(       \
                    &(Wp)[(size_t)(cp * 128 + scol) * (ldk) + (st) * 128 +    \
                          kk * 32 + sscn * 8]);                               \
        }                                                                     \
    }
#define WRITE_W()                                                             \
    {                                                                         \
        _Pragma("unroll")                                                     \
        for (int cp = 0; cp < 2; ++cp) {                                      \
            _Pragma("unroll")                                                 \
            for (int kk = 0; kk < 4; ++kk)                                    \
                *reinterpret_cast<ushort8v*>(                                 \
                    &Bs[kk][sscn][cp * 128 + scol][0]) = wreg[cp * 4 + kk];   \
        }                                                                     \
    }

    auto compute_p1 = [&](int st) {
#pragma unroll
        for (int kk = 0; kk < 4; ++kk) {
            bf16x8 af[2];
#pragma unroll
            for (int i = 0; i < 2; ++i)
                af[i] = __builtin_bit_cast(bf16x8,
                    *reinterpret_cast<const ushort8v*>(&As[st * 4 + kk][kc][wr * 32 + i * 16 + fr][0]));
#pragma unroll
            for (int j = 0; j < 4; ++j) {
                bf16x8 bf = __builtin_bit_cast(bf16x8,
                    *reinterpret_cast<const ushort8v*>(&Bs[kk][kc][wc * 64 + j * 16 + fr][0]));
#pragma unroll
                for (int i = 0; i < 2; ++i)
                    acc[i][j] = __builtin_amdgcn_mfma_f32_16x16x32_bf16(af[i], bf, acc[i][j], 0, 0, 0);
            }
        }
    };
    auto compute_p2 = [&](int st) {
#pragma unroll
        for (int kk = 0; kk < 4; ++kk) {
            bf16x8 af[2];
#pragma unroll
            for (int i = 0; i < 2; ++i)
                af[i] = __builtin_bit_cast(bf16x8,
                    *reinterpret_cast<const ushort8v*>(&Ts[st * 4 + kk][kc][wr * 32 + i * 16 + fr][0]));
#pragma unroll
            for (int j = 0; j < 4; ++j) {
                bf16x8 bf = __builtin_bit_cast(bf16x8,
                    *reinterpret_cast<const ushort8v*>(&Bs[kk][kc][wc * 64 + j * 16 + fr][0]));
#pragma unroll
                for (int i = 0; i < 2; ++i)
                    acc[i][j] = __builtin_amdgcn_mfma_f32_16x16x32_bf16(af[i], bf, acc[i][j], 0, 0, 0);
            }
        }
    };
    auto epilogue1 = [&]() {
#pragma unroll
        for (int i = 0; i < 2; ++i)
#pragma unroll
            for (int j = 0; j < 4; ++j) {
                int col = wc * 64 + j * 16 + fr;
                float bb = b1[col];
#pragma unroll
                for (int jj = 0; jj < 4; ++jj) {
                    int row = wr * 32 + i * 16 + kc * 4 + jj;
                    float v = fmaxf(acc[i][j][jj] + bb, 0.f);
                    Ts[col >> 5][(col >> 3) & 3][row][col & 7] = f2bf(v);
                }
                acc[i][j] = (f32x4){0.f, 0.f, 0.f, 0.f};
            }
    };

    // ---- W1 st0 -> regs; stage full A tile; regs -> LDS
    LOAD_W(Wt1, K, 0);
    {
        int row = tid >> 3, c0 = tid & 7;
        int gr = m0 + row;
#pragma unroll
        for (int i = 0; i < K / 64; ++i) {
            int chunk = c0 + i * 8;
            ushort8v av = {0, 0, 0, 0, 0, 0, 0, 0};
            if (gr < M) av = *reinterpret_cast<const ushort8v*>(&A[(size_t)gr * K + chunk * 8]);
            *reinterpret_cast<ushort8v*>(&As[chunk >> 2][chunk & 3][row][0]) = av;
        }
    }
    WRITE_W();
    // prefetch next slice while st0 is consumed
    if (NST1 > 1) { LOAD_W(Wt1, K, 1); } else { LOAD_W(Wt2, 256, 0); }
    __syncthreads();               // As + Bs(st0) ready
    compute_p1(0);
    if (NST1 == 1) epilogue1();
    __syncthreads();               // Bs consumed (+Ts ready if NST1==1)
    WRITE_W();
    if (NST1 > 1) { LOAD_W(Wt2, 256, 0); } else { LOAD_W(Wt2, 256, 1); }
    __syncthreads();               // Bs ready
    if (NST1 > 1) {
        compute_p1(1);
        epilogue1();
        __syncthreads();           // Bs consumed + Ts ready
        WRITE_W();                 // W2 st0
        LOAD_W(Wt2, 256, 1);
        __syncthreads();           // Bs ready
    }
    compute_p2(0);
    __syncthreads();               // Bs consumed
    WRITE_W();                     // W2 st1
    __syncthreads();               // Bs ready
    compute_p2(1);

    // ---- epilogue 2 -> global
#pragma unroll
    for (int i = 0; i < 2; ++i)
#pragma unroll
        for (int j = 0; j < 4; ++j) {
            int col = wc * 64 + j * 16 + fr;
            float bb = b2[col];
#pragma unroll
            for (int jj = 0; jj < 4; ++jj) {
                int row = m0 + wr * 32 + i * 16 + kc * 4 + jj;
                if (row < M) {
                    float v = fmaxf(acc[i][j][jj] + bb, 0.f);
                    if (OUT_BF16)
                        ((unsigned short*)C)[(size_t)row * 256 + col] = f2bf(v);
                    else
                        ((float*)C)[(size_t)row * 256 + col] = v;
                }
            }
        }
#undef LOAD_W
#undef WRITE_W
}

extern "C" void kernel_launch(void* const* d_in, const int* in_sizes, int n_in,
                              void* d_out, int out_size, void* d_ws, size_t ws_size,
                              hipStream_t stream) {
    const float* x = (const float*)d_in[0];
    const int* eb = (const int*)d_in[1];
    const int E = NEDGES;
    const int N = NNODES;

    const float* w1[3] = {(const float*)d_in[2], (const float*)d_in[6], (const float*)d_in[10]};
    const float* b1[3] = {(const float*)d_in[3], (const float*)d_in[7], (const float*)d_in[11]};
    const float* w2[3] = {(const float*)d_in[4], (const float*)d_in[8], (const float*)d_in[12]};
    const float* b2[3] = {(const float*)d_in[5], (const float*)d_in[9], (const float*)d_in[13]};

    // workspace layout
    char* ws = (char*)d_ws;
    size_t off = 0;
    auto alloc = [&](size_t bytes) {
        void* p = ws + off;
        off += (bytes + 255) & ~(size_t)255;
        return p;
    };
    int* flag   = (int*)alloc(4);
    int* cnt    = (int*)alloc((size_t)N * 4);
    int* offs   = (int*)alloc((size_t)(N + 1) * 4);
    int* cursor = (int*)alloc((size_t)N * 4);
    int* srcs   = (int*)alloc((size_t)E * 4);
    unsigned short* xb   = (unsigned short*)alloc((size_t)N * DIN * 2);
    unsigned short* zbuf = (unsigned short*)alloc((size_t)N * DH * 2);
    unsigned short* hbuf = (unsigned short*)alloc((size_t)N * DH * 2);
    unsigned short* wt[6];
    wt[0] = (unsigned short*)alloc((size_t)DIN * DH * 2);          // w1_0^T: 256x128
    for (int i = 1; i < 6; ++i) wt[i] = (unsigned short*)alloc((size_t)DH * DH * 2);
    (void)ws_size; (void)n_in; (void)out_size; (void)in_sizes;

    // --- fused prep (zero cnt | detect | x->bf16 | weights ->bf16 transposed)
    PrepArgs pa;
    pa.wsrc[0] = w1[0]; pa.wsrc[1] = w2[0]; pa.wsrc[2] = w1[1];
    pa.wsrc[3] = w2[1]; pa.wsrc[4] = w1[2]; pa.wsrc[5] = w2[2];
    for (int i = 0; i < 6; ++i) pa.wdst[i] = wt[i];
    pa.wkbits[0] = 7;
    for (int i = 1; i < 6; ++i) pa.wkbits[i] = 8;
    pa.eb = eb; pa.flag = flag; pa.cnt = cnt; pa.x = x; pa.xb = xb;
    prep_kernel<<<PREP_GRID, 256, 0, stream>>>(pa);

    // --- CSR build
    hist_kernel<<<(E + 255) / 256, 256, 0, stream>>>(eb, flag, cnt, E);
    scan_kernel<<<1, 1024, 0, stream>>>(cnt, offs, cursor, N);
    scatter_kernel<<<(E + 255) / 256, 256, 0, stream>>>(eb, flag, cursor, srcs, E);

    int mlp_grid = (N + 63) / 64;               // 157 blocks
    int agg_blocks_256 = ((N + 31) / 32) * 4;   // D=256: 32 nodes/block, 4 slices
    int agg_blocks_128 = ((N + 31) / 32) * 2;   // D=128: 32 nodes/block, 2 slices

    // --- layer 0 (K = 128)
    agg_add_sliced_kernel<128><<<agg_blocks_128, 256, 0, stream>>>(xb, srcs, offs, hbuf, N);
    mlp_fused_kernel<128, 1><<<mlp_grid, 512, 0, stream>>>(hbuf, wt[0], b1[0], wt[1], b2[0], zbuf, N);

    // --- layer 1
    agg_add_sliced_kernel<256><<<agg_blocks_256, 256, 0, stream>>>(zbuf, srcs, offs, hbuf, N);
    mlp_fused_kernel<256, 1><<<mlp_grid, 512, 0, stream>>>(hbuf, wt[2], b1[1], wt[3], b2[1], zbuf, N);

    // --- layer 2 (final output fp32 to d_out)
    agg_add_sliced_kernel<256><<<agg_blocks_256, 256, 0, stream>>>(zbuf, srcs, offs, hbuf, N);
    mlp_fused_kernel<256, 0><<<mlp_grid, 512, 0, stream>>>(hbuf, wt[4], b1[2], wt[5], b2[2], (float*)d_out, N);
}

// Round 17
// 145.937 us; speedup vs baseline: 1.0713x; 1.0051x over previous
//
#include <hip/hip_runtime.h>
#include <hip/hip_bf16.h>
#include <cstdint>

// ---------------------------------------------------------------------------
// GNN encoder: 3 x { agg = segment_sum(z[src], dst); h = z + agg;
//                    t = relu(h@w1+b1); z = relu(t@w2+b2) }
// CSR build per call. z bf16 between layers.
// agg r17: 128B-slice gather + SOFTWARE-PIPELINED srcs prefetch (next round's
// 4 indices loaded during current round's gathers/FMAs -> 1 L2 round-trip
// per round instead of 2). Chain->edge mapping unchanged -> bitwise-same.
// MLP: r16 (64-row, 8 waves, 32x64 wave tiles, T14 reg-prefetch staging).
// scan: wave-shuffle. wconv: coalesced LDS transpose.
// ---------------------------------------------------------------------------

#define NNODES 10000
#define NEDGES 320000
#define DIN 128
#define DH 256

typedef __bf16 bf16x8 __attribute__((ext_vector_type(8)));
typedef unsigned short ushort8v __attribute__((ext_vector_type(8)));
typedef unsigned short ushort4v __attribute__((ext_vector_type(4)));
typedef float f32x4 __attribute__((ext_vector_type(4)));

__device__ __forceinline__ unsigned short f2bf(float f) {
    unsigned int u = __float_as_uint(f);
    unsigned int r = u + 0x7fffu + ((u >> 16) & 1u);   // round-to-nearest-even
    return (unsigned short)(r >> 16);
}
__device__ __forceinline__ float bf2f(unsigned short u) {
    return __uint_as_float(((unsigned int)u) << 16);
}

// --- fused prep: [0,40) zero cnt | [40] detect i32/i64 | [41,1291) xconv |
// rest: wconv via coalesced 32x32 LDS-transpose tiles
struct PrepArgs {
    const float* wsrc[6];
    unsigned short* wdst[6];
    int wkbits[6];
    const int* eb;
    int* flag;
    int* cnt;
    const float* x;
    unsigned short* xb;
};
#define PREP_ZERO_B 40
#define PREP_XCONV_B 1250
#define PREP_WCONV_B 352   // 32 tiles (m0: 4x8) + 5*64 tiles (8x8)
#define PREP_GRID (PREP_ZERO_B + 1 + PREP_XCONV_B + PREP_WCONV_B)

__global__ void prep_kernel(PrepArgs a) {
    __shared__ float tile[32][33];
    __shared__ int any;
    int bid = blockIdx.x;
    int tid = threadIdx.x;
    if (bid < PREP_ZERO_B) {
        int i = bid * 256 + tid;
        if (i < NNODES) a.cnt[i] = 0;
    } else if (bid == PREP_ZERO_B) {
        if (tid == 0) any = 0;
        __syncthreads();
        for (int i = tid; i < 1024; i += 256)
            if (a.eb[2 * i + 1] != 0) any = 1;
        __syncthreads();
        if (tid == 0) a.flag[0] = any;   // 1 => int32 storage, 0 => int64
    } else if (bid < PREP_ZERO_B + 1 + PREP_XCONV_B) {
        int i = (bid - PREP_ZERO_B - 1) * 256 + tid;
        if (i < NNODES * DIN / 4) {
            float4 v = reinterpret_cast<const float4*>(a.x)[i];
            ushort4v o = {f2bf(v.x), f2bf(v.y), f2bf(v.z), f2bf(v.w)};
            reinterpret_cast<ushort4v*>(a.xb)[i] = o;
        }
    } else {
        // transpose+convert one 32x32 tile: src fp32 [K][256] -> dst bf16 [256][K]
        int wb = bid - (PREP_ZERO_B + 1 + PREP_XCONV_B);
        int m, t32;
        if (wb < 32) { m = 0; t32 = wb; }
        else { m = 1 + (wb - 32) / 64; t32 = (wb - 32) % 64; }
        int kb = a.wkbits[m];
        int K = 1 << kb;
        int tc = t32 & 7, tr = t32 >> 3;          // tr < K/32
        int r = tid >> 3, c4 = (tid & 7) * 4;     // load coalesced rows
        float4 v = *reinterpret_cast<const float4*>(
            &a.wsrc[m][(size_t)(tr * 32 + r) * 256 + tc * 32 + c4]);
        tile[r][c4 + 0] = v.x; tile[r][c4 + 1] = v.y;
        tile[r][c4 + 2] = v.z; tile[r][c4 + 3] = v.w;
        __syncthreads();
        int cc = tid >> 3, k4 = (tid & 7) * 4;    // write coalesced dst rows
        ushort4v o = {f2bf(tile[k4 + 0][cc]), f2bf(tile[k4 + 1][cc]),
                      f2bf(tile[k4 + 2][cc]), f2bf(tile[k4 + 3][cc])};
        *reinterpret_cast<ushort4v*>(
            &a.wdst[m][(size_t)(tc * 32 + cc) * K + tr * 32 + k4]) = o;
    }
}

__device__ __forceinline__ int eload(const int* __restrict__ eb, int is32, long logical_idx) {
    return is32 ? eb[logical_idx] : eb[2 * logical_idx]; // little-endian low word
}

__global__ void hist_kernel(const int* __restrict__ eb, const int* __restrict__ flag,
                            int* __restrict__ cnt, int E) {
    int i = blockIdx.x * blockDim.x + threadIdx.x;
    if (i >= E) return;
    int is32 = flag[0];
    int d = eload(eb, is32, (long)E + i);
    atomicAdd(&cnt[d], 1);
}

// single-block exclusive scan over N counts -> offs[N+1], cursor copy.
// Wave-shuffle scan: per-wave __shfl_up inclusive scan, 16 wave sums scanned
// by wave 0, 2 barriers total.
__global__ __launch_bounds__(1024) void scan_kernel(const int* __restrict__ cnt,
                                                    int* __restrict__ offs,
                                                    int* __restrict__ cursor, int n) {
    __shared__ int wsums[16];
    int tid = threadIdx.x, lane = tid & 63, wid = tid >> 6;
    int per = (n + 1023) / 1024;          // 10 for n=10000
    int beg = tid * per;
    int local[16];
    int s = 0;
    for (int i = 0; i < per; ++i) {
        int idx = beg + i;
        int v = (idx < n) ? cnt[idx] : 0;
        local[i] = s;
        s += v;
    }
    int inc = s;                           // inclusive scan within wave
    for (int d = 1; d < 64; d <<= 1) {
        int y = __shfl_up(inc, d, 64);
        if (lane >= d) inc += y;
    }
    if (lane == 63) wsums[wid] = inc;
    __syncthreads();
    if (tid < 16) {
        int v = wsums[tid];
        for (int d = 1; d < 16; d <<= 1) {
            int y = __shfl_up(v, d, 64);
            if (tid >= d) v += y;
        }
        wsums[tid] = v;                    // inclusive wave-sum prefix
    }
    __syncthreads();
    int wbase = (wid > 0) ? wsums[wid - 1] : 0;
    int base = wbase + inc - s;            // exclusive prefix of this chunk
    for (int i = 0; i < per; ++i) {
        int idx = beg + i;
        if (idx < n) {
            int v = base + local[i];
            offs[idx] = v;
            cursor[idx] = v;
        }
    }
    if (tid == 1023) offs[n] = wbase + inc;
}

__global__ void scatter_kernel(const int* __restrict__ eb, const int* __restrict__ flag,
                               int* __restrict__ cursor, int* __restrict__ srcs, int E) {
    int i = blockIdx.x * blockDim.x + threadIdx.x;
    if (i >= E) return;
    int is32 = flag[0];
    int s = eload(eb, is32, (long)i);
    int d = eload(eb, is32, (long)E + i);
    int pos = atomicAdd(&cursor[d], 1);
    srcs[pos] = s;
}

// --- sliced bf16 aggregation: h[i] = z[i] + sum_{e in CSR[i]} z[src_e].
// 128B slices: LPN=8 lanes x ushort8 (16B) = one 128B cache line per
// node-slice. slice = bid & (NSLICE-1) -> round-robin XCD binding; per-XCD
// working set N*128B = 1.28 MB (L2-resident). 4 gather chains + software-
// pipelined srcs prefetch (next round's indices load during current gathers).
template <int D>
__global__ __launch_bounds__(256) void agg_add_sliced_kernel(const unsigned short* __restrict__ z,
                                                             const int* __restrict__ srcs,
                                                             const int* __restrict__ offs,
                                                             unsigned short* __restrict__ h, int n) {
    constexpr int NSLICE = (D * 2) / 128;  // 4 for D=256, 2 for D=128
    constexpr int LPN = 8;                 // 8 lanes x 16B = 128B per node-slice
    constexpr int NPB = 256 / LPN;         // 32 nodes per block
    int bid = blockIdx.x;
    int slice = bid & (NSLICE - 1);
    int ng = bid / NSLICE;
    int t = threadIdx.x;
    int node = ng * NPB + t / LPN;
    if (node >= n) return;
    int li = t % LPN;
    int col8 = slice * LPN + li;          // ushort8 column index within row
    const ushort8v* zb = reinterpret_cast<const ushort8v*>(z);
    const int ld8 = D / 8;
    int beg = offs[node], end = offs[node + 1];

    float a0[8] = {}, a1[8] = {}, a2[8] = {}, a3[8] = {};
    int e = beg;
    if (e + 4 <= end) {
        // prologue: round 0's indices
        int s0 = srcs[e], s1 = srcs[e + 1], s2 = srcs[e + 2], s3 = srcs[e + 3];
        while (true) {
            // prefetch next round's indices (in flight during gathers + FMAs)
            int n0 = 0, n1 = 0, n2 = 0, n3 = 0;
            bool more = (e + 8 <= end);
            if (more) {
                n0 = srcs[e + 4]; n1 = srcs[e + 5];
                n2 = srcs[e + 6]; n3 = srcs[e + 7];
            }
            ushort8v v0 = zb[(size_t)s0 * ld8 + col8];
            ushort8v v1 = zb[(size_t)s1 * ld8 + col8];
            ushort8v v2 = zb[(size_t)s2 * ld8 + col8];
            ushort8v v3 = zb[(size_t)s3 * ld8 + col8];
#pragma unroll
            for (int j = 0; j < 8; ++j) {
                a0[j] += bf2f(v0[j]);
                a1[j] += bf2f(v1[j]);
                a2[j] += bf2f(v2[j]);
                a3[j] += bf2f(v3[j]);
            }
            e += 4;
            if (!more) break;
            s0 = n0; s1 = n1; s2 = n2; s3 = n3;
        }
    }
    for (; e < end; ++e) {
        ushort8v v = zb[(size_t)srcs[e] * ld8 + col8];
#pragma unroll
        for (int j = 0; j < 8; ++j) a0[j] += bf2f(v[j]);
    }
    ushort8v zr = zb[(size_t)node * ld8 + col8];   // residual z term
    ushort8v o;
#pragma unroll
    for (int j = 0; j < 8; ++j) {
        float v = a0[j] + a1[j] + a2[j] + a3[j] + bf2f(zr[j]);
        o[j] = f2bf(v);
    }
    reinterpret_cast<ushort8v*>(h)[(size_t)node * ld8 + col8] = o;
}

// --- fused MLP r16: C = relu( relu(A@W1+b1) @ W2 + b2 ).
// 512 threads / 8 waves; wave grid 2x4 (wr=wave>>2, wc=wave&3), 32x64/wave.
// T14 async-stage: next W slice -> 8 ushort8v regs during current MFMA;
// regs -> LDS after consumed-barrier. Same Bs slots, same k-order.
// MFMA layouts (m89-verified): A-frag row=lane&15, k=(lane>>4)*8+j;
// C/D col=lane&15, row=(lane>>4)*4+j.
template <int K, int OUT_BF16>
__global__ __launch_bounds__(512) void mlp_fused_kernel(const unsigned short* __restrict__ A,
                                                        const unsigned short* __restrict__ Wt1,
                                                        const float* __restrict__ b1,
                                                        const unsigned short* __restrict__ Wt2,
                                                        const float* __restrict__ b2,
                                                        void* __restrict__ C, int M) {
    constexpr int NK = K / 32;                   // k-chunks in A (4 or 8)
    constexpr int NST1 = K / 128;                // phase-1 W stages (1 or 2)
    __shared__ unsigned short As[NK][4][64][8];  // 16/32 KB  full A tile
    __shared__ unsigned short Bs[4][4][256][8];  // 64 KB     128-k x 256-col W slice
    __shared__ unsigned short Ts[8][4][64][8];   // 32 KB     t tile
    int tid = threadIdx.x;
    int wave = tid >> 6, lane = tid & 63;
    int wr = wave >> 2, wc = wave & 3;           // 2x4 wave grid
    int m0 = blockIdx.x * 64;
    int fr = lane & 15;        // fragment row/col
    int kc = lane >> 4;        // fragment k-chunk (== rg for C/D rows)
    int scol = tid >> 2;       // staging col 0..127
    int sscn = tid & 3;        // staging k-subchunk 0..3

    f32x4 acc[2][4];
#pragma unroll
    for (int i = 0; i < 2; ++i)
#pragma unroll
        for (int j = 0; j < 4; ++j) acc[i][j] = (f32x4){0.f, 0.f, 0.f, 0.f};

    ushort8v wreg[8];
#define LOAD_W(Wp, ldk, st)                                                   \
    {                                                                         \
        _Pragma("unroll")                                                     \
        for (int cp = 0; cp < 2; ++cp) {                                      \
            _Pragma("unroll")                                                 \
            for (int kk = 0; kk < 4; ++kk)                                    \
                wreg[cp * 4 + kk] = *reinterpret_cast<const ushort8v*>(       \
                    &(Wp)[(size_t)(cp * 128 + scol) * (ldk) + (st) * 128 +    \
                          kk * 32 + sscn * 8]);                               \
        }                                                                     \
    }
#define WRITE_W()                                                             \
    {                                                                         \
        _Pragma("unroll")                                                     \
        for (int cp = 0; cp < 2; ++cp) {                                      \
            _Pragma("unroll")                                                 \
            for (int kk = 0; kk < 4; ++kk)                                    \
                *reinterpret_cast<ushort8v*>(                                 \
                    &Bs[kk][sscn][cp * 128 + scol][0]) = wreg[cp * 4 + kk];   \
        }                                                                     \
    }

    auto compute_p1 = [&](int st) {
#pragma unroll
        for (int kk = 0; kk < 4; ++kk) {
            bf16x8 af[2];
#pragma unroll
            for (int i = 0; i < 2; ++i)
                af[i] = __builtin_bit_cast(bf16x8,
                    *reinterpret_cast<const ushort8v*>(&As[st * 4 + kk][kc][wr * 32 + i * 16 + fr][0]));
#pragma unroll
            for (int j = 0; j < 4; ++j) {
                bf16x8 bf = __builtin_bit_cast(bf16x8,
                    *reinterpret_cast<const ushort8v*>(&Bs[kk][kc][wc * 64 + j * 16 + fr][0]));
#pragma unroll
                for (int i = 0; i < 2; ++i)
                    acc[i][j] = __builtin_amdgcn_mfma_f32_16x16x32_bf16(af[i], bf, acc[i][j], 0, 0, 0);
            }
        }
    };
    auto compute_p2 = [&](int st) {
#pragma unroll
        for (int kk = 0; kk < 4; ++kk) {
            bf16x8 af[2];
#pragma unroll
            for (int i = 0; i < 2; ++i)
                af[i] = __builtin_bit_cast(bf16x8,
                    *reinterpret_cast<const ushort8v*>(&Ts[st * 4 + kk][kc][wr * 32 + i * 16 + fr][0]));
#pragma unroll
            for (int j = 0; j < 4; ++j) {
                bf16x8 bf = __builtin_bit_cast(bf16x8,
                    *reinterpret_cast<const ushort8v*>(&Bs[kk][kc][wc * 64 + j * 16 + fr][0]));
#pragma unroll
                for (int i = 0; i < 2; ++i)
                    acc[i][j] = __builtin_amdgcn_mfma_f32_16x16x32_bf16(af[i], bf, acc[i][j], 0, 0, 0);
            }
        }
    };
    auto epilogue1 = [&]() {
#pragma unroll
        for (int i = 0; i < 2; ++i)
#pragma unroll
            for (int j = 0; j < 4; ++j) {
                int col = wc * 64 + j * 16 + fr;
                float bb = b1[col];
#pragma unroll
                for (int jj = 0; jj < 4; ++jj) {
                    int row = wr * 32 + i * 16 + kc * 4 + jj;
                    float v = fmaxf(acc[i][j][jj] + bb, 0.f);
                    Ts[col >> 5][(col >> 3) & 3][row][col & 7] = f2bf(v);
                }
                acc[i][j] = (f32x4){0.f, 0.f, 0.f, 0.f};
            }
    };

    // ---- W1 st0 -> regs; stage full A tile; regs -> LDS
    LOAD_W(Wt1, K, 0);
    {
        int row = tid >> 3, c0 = tid & 7;
        int gr = m0 + row;
#pragma unroll
        for (int i = 0; i < K / 64; ++i) {
            int chunk = c0 + i * 8;
            ushort8v av = {0, 0, 0, 0, 0, 0, 0, 0};
            if (gr < M) av = *reinterpret_cast<const ushort8v*>(&A[(size_t)gr * K + chunk * 8]);
            *reinterpret_cast<ushort8v*>(&As[chunk >> 2][chunk & 3][row][0]) = av;
        }
    }
    WRITE_W();
    // prefetch next slice while st0 is consumed
    if (NST1 > 1) { LOAD_W(Wt1, K, 1); } else { LOAD_W(Wt2, 256, 0); }
    __syncthreads();               // As + Bs(st0) ready
    compute_p1(0);
    if (NST1 == 1) epilogue1();
    __syncthreads();               // Bs consumed (+Ts ready if NST1==1)
    WRITE_W();
    if (NST1 > 1) { LOAD_W(Wt2, 256, 0); } else { LOAD_W(Wt2, 256, 1); }
    __syncthreads();               // Bs ready
    if (NST1 > 1) {
        compute_p1(1);
        epilogue1();
        __syncthreads();           // Bs consumed + Ts ready
        WRITE_W();                 // W2 st0
        LOAD_W(Wt2, 256, 1);
        __syncthreads();           // Bs ready
    }
    compute_p2(0);
    __syncthreads();               // Bs consumed
    WRITE_W();                     // W2 st1
    __syncthreads();               // Bs ready
    compute_p2(1);

    // ---- epilogue 2 -> global
#pragma unroll
    for (int i = 0; i < 2; ++i)
#pragma unroll
        for (int j = 0; j < 4; ++j) {
            int col = wc * 64 + j * 16 + fr;
            float bb = b2[col];
#pragma unroll
            for (int jj = 0; jj < 4; ++jj) {
                int row = m0 + wr * 32 + i * 16 + kc * 4 + jj;
                if (row < M) {
                    float v = fmaxf(acc[i][j][jj] + bb, 0.f);
                    if (OUT_BF16)
                        ((unsigned short*)C)[(size_t)row * 256 + col] = f2bf(v);
                    else
                        ((float*)C)[(size_t)row * 256 + col] = v;
                }
            }
        }
#undef LOAD_W
#undef WRITE_W
}

extern "C" void kernel_launch(void* const* d_in, const int* in_sizes, int n_in,
                              void* d_out, int out_size, void* d_ws, size_t ws_size,
                              hipStream_t stream) {
    const float* x = (const float*)d_in[0];
    const int* eb = (const int*)d_in[1];
    const int E = NEDGES;
    const int N = NNODES;

    const float* w1[3] = {(const float*)d_in[2], (const float*)d_in[6], (const float*)d_in[10]};
    const float* b1[3] = {(const float*)d_in[3], (const float*)d_in[7], (const float*)d_in[11]};
    const float* w2[3] = {(const float*)d_in[4], (const float*)d_in[8], (const float*)d_in[12]};
    const float* b2[3] = {(const float*)d_in[5], (const float*)d_in[9], (const float*)d_in[13]};

    // workspace layout
    char* ws = (char*)d_ws;
    size_t off = 0;
    auto alloc = [&](size_t bytes) {
        void* p = ws + off;
        off += (bytes + 255) & ~(size_t)255;
        return p;
    };
    int* flag   = (int*)alloc(4);
    int* cnt    = (int*)alloc((size_t)N * 4);
    int* offs   = (int*)alloc((size_t)(N + 1) * 4);
    int* cursor = (int*)alloc((size_t)N * 4);
    int* srcs   = (int*)alloc((size_t)E * 4);
    unsigned short* xb   = (unsigned short*)alloc((size_t)N * DIN * 2);
    unsigned short* zbuf = (unsigned short*)alloc((size_t)N * DH * 2);
    unsigned short* hbuf = (unsigned short*)alloc((size_t)N * DH * 2);
    unsigned short* wt[6];
    wt[0] = (unsigned short*)alloc((size_t)DIN * DH * 2);          // w1_0^T: 256x128
    for (int i = 1; i < 6; ++i) wt[i] = (unsigned short*)alloc((size_t)DH * DH * 2);
    (void)ws_size; (void)n_in; (void)out_size; (void)in_sizes;

    // --- fused prep (zero cnt | detect | x->bf16 | weights ->bf16 transposed)
    PrepArgs pa;
    pa.wsrc[0] = w1[0]; pa.wsrc[1] = w2[0]; pa.wsrc[2] = w1[1];
    pa.wsrc[3] = w2[1]; pa.wsrc[4] = w1[2]; pa.wsrc[5] = w2[2];
    for (int i = 0; i < 6; ++i) pa.wdst[i] = wt[i];
    pa.wkbits[0] = 7;
    for (int i = 1; i < 6; ++i) pa.wkbits[i] = 8;
    pa.eb = eb; pa.flag = flag; pa.cnt = cnt; pa.x = x; pa.xb = xb;
    prep_kernel<<<PREP_GRID, 256, 0, stream>>>(pa);

    // --- CSR build
    hist_kernel<<<(E + 255) / 256, 256, 0, stream>>>(eb, flag, cnt, E);
    scan_kernel<<<1, 1024, 0, stream>>>(cnt, offs, cursor, N);
    scatter_kernel<<<(E + 255) / 256, 256, 0, stream>>>(eb, flag, cursor, srcs, E);

    int mlp_grid = (N + 63) / 64;               // 157 blocks
    int agg_blocks_256 = ((N + 31) / 32) * 4;   // D=256: 32 nodes/block, 4 slices
    int agg_blocks_128 = ((N + 31) / 32) * 2;   // D=128: 32 nodes/block, 2 slices

    // --- layer 0 (K = 128)
    agg_add_sliced_kernel<128><<<agg_blocks_128, 256, 0, stream>>>(xb, srcs, offs, hbuf, N);
    mlp_fused_kernel<128, 1><<<mlp_grid, 512, 0, stream>>>(hbuf, wt[0], b1[0], wt[1], b2[0], zbuf, N);

    // --- layer 1
    agg_add_sliced_kernel<256><<<agg_blocks_256, 256, 0, stream>>>(zbuf, srcs, offs, hbuf, N);
    mlp_fused_kernel<256, 1><<<mlp_grid, 512, 0, stream>>>(hbuf, wt[2], b1[1], wt[3], b2[1], zbuf, N);

    // --- layer 2 (final output fp32 to d_out)
    agg_add_sliced_kernel<256><<<agg_blocks_256, 256, 0, stream>>>(zbuf, srcs, offs, hbuf, N);
    mlp_fused_kernel<256, 0><<<mlp_grid, 512, 0, stream>>>(hbuf, wt[4], b1[2], wt[5], b2[2], (float*)d_out, N);
}